// Round 18
// baseline (156.003 us; speedup 1.0000x reference)
//
#include <hip/hip_runtime.h>

// CrossModalAttention  B=8, CQ=CKV=E=256, Nq=4096, Nkv=1024
// out = concat([C, (out_w@g_w@P) @ softmax(thetaC^T @ phiP / 16)^T], axis=1)

typedef __attribute__((ext_vector_type(8))) short short8;   // 8 bf16 raw
typedef __attribute__((ext_vector_type(16))) float f32x16;
typedef unsigned short ushort_t;

__device__ __forceinline__ unsigned short f2bf(float f) {
    unsigned int u = __float_as_uint(f);
    u += 0x7FFFu + ((u >> 16) & 1u);            // RNE
    return (unsigned short)(u >> 16);
}
__device__ __forceinline__ unsigned int pack2bf(float a, float b) {
    return (unsigned int)f2bf(a) | ((unsigned int)f2bf(b) << 16);
}
__device__ __forceinline__ void gload16(const ushort_t* g, ushort_t* l) {
    __builtin_amdgcn_global_load_lds(
        (const __attribute__((address_space(1))) unsigned int*)g,
        (__attribute__((address_space(3))) unsigned int*)l, 16, 0, 0);
}
__device__ __forceinline__ f32x16 zero16() {
    f32x16 z;
#pragma unroll
    for (int i = 0; i < 16; ++i) z[i] = 0.f;
    return z;
}

// ---------------- prep_w: weight chunk cvts + W2 (96 blocks, compacted) -------------
__global__ __launch_bounds__(256) void prep_w(const float* __restrict__ thw,
                                              const float* __restrict__ phw,
                                              const float* __restrict__ ow,
                                              const float* __restrict__ gw,
                                              ushort_t* __restrict__ thc,
                                              ushort_t* __restrict__ phc,
                                              ushort_t* __restrict__ w2c) {
    int blk = blockIdx.x;
    int t = threadIdx.x;
    if (blk < 64) {
        int which = blk >> 5;
        int e0 = (blk & 31) * 8;
        const float* src = which ? phw : thw;
        ushort_t* dst = which ? phc : thc;
#pragma unroll
        for (int i = 0; i < 8; ++i) {
            int e = e0 + i, c = t;
            int idx = ((((e >> 5) * 16 + (c >> 4)) * 64 + ((c >> 3) & 1) * 32 + (e & 31)) << 3) + (c & 7);
            dst[idx] = f2bf(src[e * 256 + c]);
        }
    } else {
        int c0 = (blk - 64) * 8;
        float acc[8] = {};
        for (int e = 0; e < 256; ++e) {
            float g = gw[e * 256 + t];
#pragma unroll
            for (int i = 0; i < 8; ++i) acc[i] += ow[(c0 + i) * 256 + e] * g;
        }
#pragma unroll
        for (int i = 0; i < 8; ++i) {
            int c = c0 + i, k = t;
            int idx = ((((c >> 5) * 16 + (k >> 4)) * 64 + ((k >> 3) & 1) * 32 + (c & 31)) << 3) + (k & 7);
            w2c[idx] = f2bf(acc[i]);
        }
    }
}

// ---------------- proj_all v3: chunked bf16 B-frag LDS tile, b128 frag reads --------
__global__ __launch_bounds__(256, 4) void proj_all(const ushort_t* __restrict__ thc,
                                                   const ushort_t* __restrict__ phc,
                                                   const ushort_t* __restrict__ w2c,
                                                   const float* __restrict__ C,
                                                   const float* __restrict__ P,
                                                   ushort_t* __restrict__ thetaA,
                                                   ushort_t* __restrict__ phiA,
                                                   ushort_t* __restrict__ gVx) {
    __shared__ __align__(16) ushort_t Xc[16384];   // 32 KB chunked B-frag tile
    int blk = blockIdx.x;
    int tid = threadIdx.x, lane = tid & 63, wid = tid >> 6;
    int l31 = lane & 31, lh = lane >> 5;
    const int wq = wid & 1, we = wid >> 1;

    int role, b, nt, N;
    const ushort_t* Wc;
    const float* Xg;
    ushort_t* outp;
    float scale = 1.f;
    if (blk < 512) {
        role = 0; b = blk & 7; nt = blk >> 3;
        Wc = thc; Xg = C + (size_t)b * 1048576; outp = thetaA + (size_t)b * 1048576;
        N = 4096; scale = 1.4426950408889634f / 16.0f;
    } else if (blk < 640) {
        int r = blk - 512; role = 1; b = r & 7; nt = r >> 3;
        Wc = phc; Xg = P + (size_t)b * 262144; outp = phiA + (size_t)b * 262144;
        N = 1024;
    } else {
        int r = blk - 640; role = 2; b = r & 7; nt = r >> 3;
        Wc = w2c; Xg = P + (size_t)b * 262144; outp = gVx + (size_t)b * 262144;
        N = 1024;
    }

    {
        const float* Xb = Xg + nt * 64;
        const int q = lane;
        const int sq = q >> 5, sl = q & 31;
#pragma unroll
        for (int it = 0; it < 16; ++it) {
            int ch0 = wid * 4 + it * 16;
            float v0 = Xb[(size_t)(ch0 + 0) * N + q];
            float v1 = Xb[(size_t)(ch0 + 1) * N + q];
            float v2 = Xb[(size_t)(ch0 + 2) * N + q];
            float v3 = Xb[(size_t)(ch0 + 3) * N + q];
            uint2 w;
            w.x = pack2bf(v0, v1);
            w.y = pack2bf(v2, v3);
            int ks = ch0 >> 4;
            int slh = (ch0 >> 3) & 1;
            size_t a = ((size_t)(ks * 2 + sq) * 64 + slh * 32 + sl) * 8 + (ch0 & 7);
            *(uint2*)&Xc[a] = w;
        }
    }
    __syncthreads();

    const int n0 = nt * 64 + wq * 32;
    const int ncr = (n0 >> 5) * 16;

    f32x16 o[4];
#pragma unroll
    for (int f = 0; f < 4; ++f) o[f] = zero16();

#pragma unroll
    for (int ks = 0; ks < 16; ++ks) {
        short8 xf = *(const short8*)(Xc + ((size_t)(ks * 2 + wq) * 64 + lane) * 8);
#pragma unroll
        for (int f2 = 0; f2 < 4; ++f2) {
            int f = we * 4 + f2;
            short8 wf = *(const short8*)(Wc + ((size_t)(f * 16 + ks) * 64 + lane) * 8);
            o[f2] = __builtin_amdgcn_mfma_f32_32x32x16_bf16(wf, xf, o[f2], 0, 0, 0);
        }
    }

    if (role < 2) {
#pragma unroll
        for (int f2 = 0; f2 < 4; ++f2) {
            int f = we * 4 + f2;
#pragma unroll
            for (int rq = 0; rq < 4; ++rq) {
                uint2 st;
                st.x = pack2bf(o[f2][4 * rq + 0] * scale, o[f2][4 * rq + 1] * scale);
                st.y = pack2bf(o[f2][4 * rq + 2] * scale, o[f2][4 * rq + 3] * scale);
                size_t addr = ((size_t)(ncr + f * 2 + (rq >> 1)) * 64 + l31 + 32 * (rq & 1)) * 8 + 4 * lh;
                *(uint2*)(outp + addr) = st;
            }
        }
    } else {
        int kvq = (n0 >> 4) + (l31 >> 4);
        int lhw = 32 * ((l31 >> 3) & 1);
        int kl = l31 & 7;
#pragma unroll
        for (int f2 = 0; f2 < 4; ++f2) {
            int f = we * 4 + f2;
#pragma unroll
            for (int r2 = 0; r2 < 16; ++r2) {
                int crow = (r2 & 3) + 8 * (r2 >> 2) + 4 * lh;
                size_t addr = ((size_t)(f * 64 + kvq) * 64 + crow + lhw) * 8 + kl;
                outp[addr] = f2bf(o[f2][r2]);
            }
        }
    }
}

// ---------------- attn13: 16 waves, wave-specialized producer/consumer --------------
// Grid 256 = 8b x 32qt (q-tile 128). 16 waves = 4 qg(32q) x 4 zz.
// zz<2: compute QK kv-frag zz + softmax + publish.  zz==2: K-stager. zz==3: V-stager + C-copy half.
// ALL waves: PV for e-quarter zz (o[2]). kv-tile 64, K/V double-buffered, K 2-ahead, V 1-ahead.
__global__ __launch_bounds__(1024) void attn13(const ushort_t* __restrict__ thetaA,
                                               const ushort_t* __restrict__ phiA,
                                               const ushort_t* __restrict__ gVx,
                                               const float* __restrict__ Cf,
                                               float* __restrict__ out) {
    const int b = blockIdx.x & 7, qt = blockIdx.x >> 3;   // batch == XCD
    const int tid = threadIdx.x, lane = tid & 63, wid = tid >> 6;   // wid 0..15
    const int l31 = lane & 31, lh = lane >> 5;
    const int qg = wid & 3, zz = wid >> 2;                // zz 0..3

    __shared__ __align__(16) ushort_t smem[65536];        // K[2][16384] | V: 32768+[2][16384]
    __shared__ __align__(16) ushort_t Pl[8192];           // 16 P-frags x 1 KB
    __shared__ float rlS[2][4][32];

    const ushort_t* thA = thetaA + (size_t)b * 1048576;
    const ushort_t* phA = phiA + (size_t)b * 262144;
    const ushort_t* gVb = gVx + (size_t)b * 262144;

    // K-stagers: zz==2 (4 waves), 8 chunks of 1 KB each
    auto stageK = [&](int j) {
        if (zz == 2) {
            int w = wid - 8;                               // 0..3
#pragma unroll
            for (int i = 0; i < 8; ++i) {
                int ch = w * 8 + i;                        // 0..31
                const ushort_t* src = phA + (size_t)j * 16384 + (size_t)ch * 512 + lane * 8;
                gload16(src, smem + (j & 1) * 16384 + ch * 512);
            }
        }
    };
    // V-stagers: zz==3 (4 waves), 8 chunks each: f = v*2 + (i>>2), kvq = j*4 + (i&3)
    auto stageV = [&](int j) {
        if (zz == 3) {
            int v = wid - 12;                              // 0..3
#pragma unroll
            for (int i = 0; i < 8; ++i) {
                int f = v * 2 + (i >> 2);
                int kq = j * 4 + (i & 3);
                const ushort_t* src = gVb + ((size_t)(f * 64 + kq) * 64 + lane) * 8;
                gload16(src, smem + 32768 + (j & 1) * 16384 + f * 2048 + (i & 3) * 512);
            }
        }
    };

    stageK(0); stageV(0);

    // Q B-frags (compute waves only)
    short8 qf[16];
    if (zz < 2) {
        const int qcr = (qt * 4 + qg) * 16;
#pragma unroll
        for (int ks = 0; ks < 16; ++ks)
            qf[ks] = *(const short8*)(thA + ((size_t)(qcr + ks) * 64 + lane) * 8);
    }

    asm volatile("s_waitcnt vmcnt(0)" ::: "memory");
    __builtin_amdgcn_s_barrier();
    __builtin_amdgcn_sched_barrier(0);
    stageK(1);

    f32x16 o[2];
    o[0] = zero16(); o[1] = zero16();
    float rl = 0.f;

    // C-copy (stager threads, 512 of them, 1 float4 per region)
    const size_t cbase = (size_t)b * 1048576 + (size_t)qt * 128;
    const size_t dofs = (size_t)b * 1048576;
    size_t cpo = 0;
    float4 cpv;

    for (int it = 0; it < 16; ++it) {
        // ---- compute waves: QK(it) + softmax + pack + publish ----
        if (zz < 2) {
            const ushort_t* Kb = smem + (it & 1) * 16384 + zz * 8192;   // kv-frag zz
            f32x16 s = zero16();
            __builtin_amdgcn_s_setprio(1);
#pragma unroll
            for (int ks = 0; ks < 16; ++ks) {
                short8 kf = *(const short8*)(Kb + (size_t)ks * 512 + lane * 8);
                s = __builtin_amdgcn_mfma_f32_32x32x16_bf16(kf, qf[ks], s, 0, 0, 0);
            }
            __builtin_amdgcn_s_setprio(0);
#pragma unroll
            for (int r = 0; r < 16; ++r) s[r] = __builtin_amdgcn_exp2f(s[r]);
            float t0 = (s[0] + s[1]) + (s[2] + s[3]);
            float t1 = (s[4] + s[5]) + (s[6] + s[7]);
            float t2 = (s[8] + s[9]) + (s[10] + s[11]);
            float t3 = (s[12] + s[13]) + (s[14] + s[15]);
            float ps = (t0 + t1) + (t2 + t3);
            ps += __shfl_xor(ps, 32);
            rl += ps;

            unsigned int a0 = pack2bf(s[0], s[1]),   b0 = pack2bf(s[4], s[5]);
            unsigned int a1 = pack2bf(s[2], s[3]),   b1 = pack2bf(s[6], s[7]);
            unsigned int a2 = pack2bf(s[8], s[9]),   b2 = pack2bf(s[12], s[13]);
            unsigned int a3 = pack2bf(s[10], s[11]), b3 = pack2bf(s[14], s[15]);
            asm volatile("v_permlane32_swap_b32 %0, %1" : "+v"(a0), "+v"(b0));
            asm volatile("v_permlane32_swap_b32 %0, %1" : "+v"(a1), "+v"(b1));
            asm volatile("v_permlane32_swap_b32 %0, %1" : "+v"(a2), "+v"(b2));
            asm volatile("v_permlane32_swap_b32 %0, %1" : "+v"(a3), "+v"(b3));
            union PW { unsigned int u[4]; short8 v; };
            PW pw0, pw1;
            pw0.u[0] = a0; pw0.u[1] = a1; pw0.u[2] = b0; pw0.u[3] = b1;
            pw1.u[0] = a2; pw1.u[1] = a3; pw1.u[2] = b2; pw1.u[3] = b3;
            *(short8*)(Pl + ((size_t)(qg * 4 + 2 * zz + 0) * 64 + lane) * 8) = pw0.v;
            *(short8*)(Pl + ((size_t)(qg * 4 + 2 * zz + 1) * 64 + lane) * 8) = pw1.v;
        }

        // ---- B1: stage(it) complete (stagers: counted, C-load rides), P visible ----
        if (it == 0) asm volatile("s_waitcnt vmcnt(0)" ::: "memory");
        else         asm volatile("s_waitcnt vmcnt(1)" ::: "memory");
        asm volatile("s_waitcnt lgkmcnt(0)" ::: "memory");
        __builtin_amdgcn_s_barrier();
        __builtin_amdgcn_sched_barrier(0);

        // ---- stagers: C-store(prev), prefetch K(it+2)/V(it+1), C-load(it) ----
        if (zz >= 2) {
            if (it >= 1) *(float4*)(out + cpo + dofs) = cpv;
            if (it <= 13) stageK(it + 2);
            if (it <= 14) stageV(it + 1);
            __builtin_amdgcn_sched_barrier(0);   // stages issued before C-load
            int idx = it * 512 + (tid - 512);
            cpo = cbase + (size_t)(idx >> 5) * 4096 + (idx & 31) * 4;
            cpv = *(const float4*)(Cf + cpo);
        }

        // ---- PV(it): all 16 waves, e-quarter zz ----
        const ushort_t* Vb = smem + 32768 + (it & 1) * 16384 + zz * 4096;
        __builtin_amdgcn_s_setprio(1);
#pragma unroll
        for (int j = 0; j < 4; ++j) {
            short8 pf = *(const short8*)(Pl + ((size_t)(qg * 4 + j) * 64 + lane) * 8);
#pragma unroll
            for (int fl = 0; fl < 2; ++fl) {
                short8 vf = *(const short8*)(Vb + (size_t)fl * 2048 + j * 512 + lane * 8);
                o[fl] = __builtin_amdgcn_mfma_f32_32x32x16_bf16(vf, pf, o[fl], 0, 0, 0);
            }
        }
        __builtin_amdgcn_s_setprio(0);
        __builtin_amdgcn_sched_barrier(0);
        __builtin_amdgcn_s_barrier();            // B2: Pl/V reads done before next publish/stage
    }

    if (zz >= 2) *(float4*)(out + cpo + dofs) = cpv;   // last copy slice

    // ---- merge rl halves, normalized store (disjoint e-quarter x q per wave) ----
    if (zz < 2 && lane < 32) rlS[zz][qg][l31] = rl;
    __syncthreads();
    float inv = 1.f / (rlS[0][qg][l31] + rlS[1][qg][l31]);
    float* ob = out + (size_t)b * 2097152 + (size_t)256 * 4096 + qt * 128 + qg * 32 + l31;
#pragma unroll
    for (int fl = 0; fl < 2; ++fl) {
#pragma unroll
        for (int r = 0; r < 16; ++r) {
            int e = zz * 64 + fl * 32 + (r & 3) + 8 * (r >> 2) + 4 * lh;
            ob[(size_t)e * 4096] = o[fl][r] * inv;
        }
    }
}

// ---------------- launch ----------------

extern "C" void kernel_launch(void* const* d_in, const int* in_sizes, int n_in,
                              void* d_out, int out_size, void* d_ws, size_t ws_size,
                              hipStream_t stream) {
    const float* C       = (const float*)d_in[0];
    const float* P       = (const float*)d_in[1];
    const float* theta_w = (const float*)d_in[2];
    const float* phi_w   = (const float*)d_in[3];
    const float* g_w     = (const float*)d_in[4];
    const float* out_w   = (const float*)d_in[5];
    float* out = (float*)d_out;

    ushort_t* ws = (ushort_t*)d_ws;
    ushort_t* thetaA = ws;                        // 8,388,608
    ushort_t* phiA   = ws + 8388608;              // 2,097,152
    ushort_t* gVx    = ws + 10485760;             // 2,097,152
    ushort_t* thWc   = ws + 12582912;             // 65,536
    ushort_t* phWc   = ws + 12648448;             // 65,536
    ushort_t* w2c    = ws + 12713984;             // 65,536

    prep_w<<<96, 256, 0, stream>>>(theta_w, phi_w, out_w, g_w, thWc, phWc, w2c);
    proj_all<<<768, 256, 0, stream>>>(thWc, phWc, w2c, C, P, thetaA, phiA, gVx);
    attn13<<<256, 1024, 0, stream>>>(thetaA, phiA, gVx, C, out);
}

// Round 20
// 103.796 us; speedup vs baseline: 1.5030x; 1.5030x over previous
//
#include <hip/hip_runtime.h>

// CrossModalAttention  B=8, CQ=CKV=E=256, Nq=4096, Nkv=1024
// out = concat([C, (out_w@g_w@P) @ softmax(thetaC^T @ phiP / 16)^T], axis=1)

typedef __attribute__((ext_vector_type(8))) short short8;   // 8 bf16 raw
typedef __attribute__((ext_vector_type(16))) float f32x16;
typedef unsigned short ushort_t;

__device__ __forceinline__ unsigned short f2bf(float f) {
    unsigned int u = __float_as_uint(f);
    u += 0x7FFFu + ((u >> 16) & 1u);            // RNE
    return (unsigned short)(u >> 16);
}
__device__ __forceinline__ unsigned int pack2bf(float a, float b) {
    return (unsigned int)f2bf(a) | ((unsigned int)f2bf(b) << 16);
}
__device__ __forceinline__ void gload16(const ushort_t* g, ushort_t* l) {
    __builtin_amdgcn_global_load_lds(
        (const __attribute__((address_space(1))) unsigned int*)g,
        (__attribute__((address_space(3))) unsigned int*)l, 16, 0, 0);
}
__device__ __forceinline__ f32x16 zero16() {
    f32x16 z;
#pragma unroll
    for (int i = 0; i < 16; ++i) z[i] = 0.f;
    return z;
}

// ---------------- prep_w: weight chunk cvts + W2 (96 blocks, compacted) -------------
__global__ __launch_bounds__(256) void prep_w(const float* __restrict__ thw,
                                              const float* __restrict__ phw,
                                              const float* __restrict__ ow,
                                              const float* __restrict__ gw,
                                              ushort_t* __restrict__ thc,
                                              ushort_t* __restrict__ phc,
                                              ushort_t* __restrict__ w2c) {
    int blk = blockIdx.x;
    int t = threadIdx.x;
    if (blk < 64) {
        int which = blk >> 5;
        int e0 = (blk & 31) * 8;
        const float* src = which ? phw : thw;
        ushort_t* dst = which ? phc : thc;
#pragma unroll
        for (int i = 0; i < 8; ++i) {
            int e = e0 + i, c = t;
            int idx = ((((e >> 5) * 16 + (c >> 4)) * 64 + ((c >> 3) & 1) * 32 + (e & 31)) << 3) + (c & 7);
            dst[idx] = f2bf(src[e * 256 + c]);
        }
    } else {
        int c0 = (blk - 64) * 8;
        float acc[8] = {};
        for (int e = 0; e < 256; ++e) {
            float g = gw[e * 256 + t];
#pragma unroll
            for (int i = 0; i < 8; ++i) acc[i] += ow[(c0 + i) * 256 + e] * g;
        }
#pragma unroll
        for (int i = 0; i < 8; ++i) {
            int c = c0 + i, k = t;
            int idx = ((((c >> 5) * 16 + (k >> 4)) * 64 + ((k >> 3) & 1) * 32 + (c & 31)) << 3) + (k & 7);
            w2c[idx] = f2bf(acc[i]);
        }
    }
}

// ---------------- proj_all v3: chunked bf16 B-frag LDS tile, b128 frag reads --------
__global__ __launch_bounds__(256, 4) void proj_all(const ushort_t* __restrict__ thc,
                                                   const ushort_t* __restrict__ phc,
                                                   const ushort_t* __restrict__ w2c,
                                                   const float* __restrict__ C,
                                                   const float* __restrict__ P,
                                                   ushort_t* __restrict__ thetaA,
                                                   ushort_t* __restrict__ phiA,
                                                   ushort_t* __restrict__ gVx) {
    __shared__ __align__(16) ushort_t Xc[16384];   // 32 KB chunked B-frag tile
    int blk = blockIdx.x;
    int tid = threadIdx.x, lane = tid & 63, wid = tid >> 6;
    int l31 = lane & 31, lh = lane >> 5;
    const int wq = wid & 1, we = wid >> 1;

    int role, b, nt, N;
    const ushort_t* Wc;
    const float* Xg;
    ushort_t* outp;
    float scale = 1.f;
    if (blk < 512) {
        role = 0; b = blk & 7; nt = blk >> 3;
        Wc = thc; Xg = C + (size_t)b * 1048576; outp = thetaA + (size_t)b * 1048576;
        N = 4096; scale = 1.4426950408889634f / 16.0f;
    } else if (blk < 640) {
        int r = blk - 512; role = 1; b = r & 7; nt = r >> 3;
        Wc = phc; Xg = P + (size_t)b * 262144; outp = phiA + (size_t)b * 262144;
        N = 1024;
    } else {
        int r = blk - 640; role = 2; b = r & 7; nt = r >> 3;
        Wc = w2c; Xg = P + (size_t)b * 262144; outp = gVx + (size_t)b * 262144;
        N = 1024;
    }

    {
        const float* Xb = Xg + nt * 64;
        const int q = lane;
        const int sq = q >> 5, sl = q & 31;
#pragma unroll
        for (int it = 0; it < 16; ++it) {
            int ch0 = wid * 4 + it * 16;
            float v0 = Xb[(size_t)(ch0 + 0) * N + q];
            float v1 = Xb[(size_t)(ch0 + 1) * N + q];
            float v2 = Xb[(size_t)(ch0 + 2) * N + q];
            float v3 = Xb[(size_t)(ch0 + 3) * N + q];
            uint2 w;
            w.x = pack2bf(v0, v1);
            w.y = pack2bf(v2, v3);
            int ks = ch0 >> 4;
            int slh = (ch0 >> 3) & 1;
            size_t a = ((size_t)(ks * 2 + sq) * 64 + slh * 32 + sl) * 8 + (ch0 & 7);
            *(uint2*)&Xc[a] = w;
        }
    }
    __syncthreads();

    const int n0 = nt * 64 + wq * 32;
    const int ncr = (n0 >> 5) * 16;

    f32x16 o[4];
#pragma unroll
    for (int f = 0; f < 4; ++f) o[f] = zero16();

#pragma unroll
    for (int ks = 0; ks < 16; ++ks) {
        short8 xf = *(const short8*)(Xc + ((size_t)(ks * 2 + wq) * 64 + lane) * 8);
#pragma unroll
        for (int f2 = 0; f2 < 4; ++f2) {
            int f = we * 4 + f2;
            short8 wf = *(const short8*)(Wc + ((size_t)(f * 16 + ks) * 64 + lane) * 8);
            o[f2] = __builtin_amdgcn_mfma_f32_32x32x16_bf16(wf, xf, o[f2], 0, 0, 0);
        }
    }

    if (role < 2) {
#pragma unroll
        for (int f2 = 0; f2 < 4; ++f2) {
            int f = we * 4 + f2;
#pragma unroll
            for (int rq = 0; rq < 4; ++rq) {
                uint2 st;
                st.x = pack2bf(o[f2][4 * rq + 0] * scale, o[f2][4 * rq + 1] * scale);
                st.y = pack2bf(o[f2][4 * rq + 2] * scale, o[f2][4 * rq + 3] * scale);
                size_t addr = ((size_t)(ncr + f * 2 + (rq >> 1)) * 64 + l31 + 32 * (rq & 1)) * 8 + 4 * lh;
                *(uint2*)(outp + addr) = st;
            }
        }
    } else {
        int kvq = (n0 >> 4) + (l31 >> 4);
        int lhw = 32 * ((l31 >> 3) & 1);
        int kl = l31 & 7;
#pragma unroll
        for (int f2 = 0; f2 < 4; ++f2) {
            int f = we * 4 + f2;
#pragma unroll
            for (int r2 = 0; r2 < 16; ++r2) {
                int crow = (r2 & 3) + 8 * (r2 >> 2) + 4 * lh;
                size_t addr = ((size_t)(f * 64 + kvq) * 64 + crow + lhw) * 8 + kl;
                outp[addr] = f2bf(o[f2][r2]);
            }
        }
    }
}

// ---------------- attn14: attn12 + Pl double-buffer, B2 dropped (1 barrier/iter) ----
// 8 waves: qg = wid&3 (32 q each), z = wid>>2.  K staged 2-ahead, V 1-ahead.
// Region: softmax(it); publish->Pl[it&1]; B1; stage/C; PV(it)||QK(it+1).  (no B2)
// LDS = 128K smem + 32K Pl = 160K exactly; rl-merge aliases dead smem in epilogue.
__global__ __launch_bounds__(512, 2) void attn14(const ushort_t* __restrict__ thetaA,
                                                 const ushort_t* __restrict__ phiA,
                                                 const ushort_t* __restrict__ gVx,
                                                 const float* __restrict__ Cf,
                                                 float* __restrict__ out) {
    const int b = blockIdx.x & 7, qt = blockIdx.x >> 3;   // batch == XCD
    const int tid = threadIdx.x, lane = tid & 63, wid = tid >> 6;
    const int l31 = lane & 31, lh = lane >> 5;
    const int qg = wid & 3, z = wid >> 2;

    __shared__ __align__(16) ushort_t smem[65536];        // K[2][16384] | V: 32768+[2][16384]
    __shared__ __align__(16) ushort_t Pl[2][8192];        // double-buffered P-exchange

    const ushort_t* thA = thetaA + (size_t)b * 1048576;
    const ushort_t* phA = phiA + (size_t)b * 262144;
    const ushort_t* gVb = gVx + (size_t)b * 262144;

    auto stageK = [&](int j) {
        if (wid < 4) {
            const ushort_t* src = phA + (size_t)j * 16384 + (size_t)wid * 4096 + lane * 8;
            ushort_t* dst = smem + (j & 1) * 16384 + wid * 4096;
#pragma unroll
            for (int i = 0; i < 8; ++i) gload16(src + i * 512, dst + i * 512);
        }
    };
    auto stageV = [&](int j) {
        if (wid >= 4) {
            int w = wid - 4;
#pragma unroll
            for (int q2 = 0; q2 < 2; ++q2) {
                int f = w * 2 + q2;
#pragma unroll
                for (int jj = 0; jj < 4; ++jj) {
                    const ushort_t* src = gVb + ((size_t)(f * 64 + j * 4 + jj) * 64 + lane) * 8;
                    ushort_t* dst = smem + 32768 + (j & 1) * 16384 + f * 2048 + jj * 512;
                    gload16(src, dst);
                }
            }
        }
    };

    stageK(0); stageV(0);

    // Q B-frags: 32 q per group, 16 k-steps
    short8 qf[16];
    {
        const int qcr = (qt * 4 + qg) * 16;
#pragma unroll
        for (int ks = 0; ks < 16; ++ks)
            qf[ks] = *(const short8*)(thA + ((size_t)(qcr + ks) * 64 + lane) * 8);
    }

    asm volatile("s_waitcnt vmcnt(0)" ::: "memory");
    __builtin_amdgcn_s_barrier();
    __builtin_amdgcn_sched_barrier(0);
    stageK(1);

    // QK(0) -> s (raw scores, kv-frag z)
    f32x16 s = zero16();
    {
        const ushort_t* Kb = smem + z * 8192;             // K[0]
#pragma unroll
        for (int ks = 0; ks < 16; ++ks) {
            short8 kf = *(const short8*)(Kb + (size_t)ks * 512 + lane * 8);
            s = __builtin_amdgcn_mfma_f32_32x32x16_bf16(kf, qf[ks], s, 0, 0, 0);
        }
    }

    f32x16 o[4];
#pragma unroll
    for (int f = 0; f < 4; ++f) o[f] = zero16();
    float rl = 0.f;

    // C-copy fold: row = it*16 + 2*wid + lh, col = qt*128 + l31*4
    const size_t cbase = (size_t)b * 1048576 + (size_t)qt * 128 + (size_t)l31 * 4;
    const size_t dofs = (size_t)b * 1048576;
    size_t cpo = 0;
    float4 cpv;

    for (int it = 0; it < 16; ++it) {
        // ---- softmax(s) in exp2 domain (no-max); tree-sum; rl partial ----
#pragma unroll
        for (int r = 0; r < 16; ++r) s[r] = __builtin_amdgcn_exp2f(s[r]);
        float t0 = (s[0] + s[1]) + (s[2] + s[3]);
        float t1 = (s[4] + s[5]) + (s[6] + s[7]);
        float t2 = (s[8] + s[9]) + (s[10] + s[11]);
        float t3 = (s[12] + s[13]) + (s[14] + s[15]);
        float ps = (t0 + t1) + (t2 + t3);
        ps += __shfl_xor(ps, 32);
        rl += ps;

        // ---- T12: s -> 2 PV B-frags; publish to Pl[it&1] ----
        unsigned int a0 = pack2bf(s[0], s[1]),   b0 = pack2bf(s[4], s[5]);
        unsigned int a1 = pack2bf(s[2], s[3]),   b1 = pack2bf(s[6], s[7]);
        unsigned int a2 = pack2bf(s[8], s[9]),   b2 = pack2bf(s[12], s[13]);
        unsigned int a3 = pack2bf(s[10], s[11]), b3 = pack2bf(s[14], s[15]);
        asm volatile("v_permlane32_swap_b32 %0, %1" : "+v"(a0), "+v"(b0));
        asm volatile("v_permlane32_swap_b32 %0, %1" : "+v"(a1), "+v"(b1));
        asm volatile("v_permlane32_swap_b32 %0, %1" : "+v"(a2), "+v"(b2));
        asm volatile("v_permlane32_swap_b32 %0, %1" : "+v"(a3), "+v"(b3));
        union PW { unsigned int u[4]; short8 v; };
        PW pw0, pw1;
        pw0.u[0] = a0; pw0.u[1] = a1; pw0.u[2] = b0; pw0.u[3] = b1;
        pw1.u[0] = a2; pw1.u[1] = a3; pw1.u[2] = b2; pw1.u[3] = b3;
        ushort_t* Pw = &Pl[it & 1][0];
        *(short8*)(Pw + ((size_t)(qg * 4 + 2 * z + 0) * 64 + lane) * 8) = pw0.v;
        *(short8*)(Pw + ((size_t)(qg * 4 + 2 * z + 1) * 64 + lane) * 8) = pw1.v;

        // ---- B1: stage(it) loads done (counted: C-load rides across), P visible ----
        if (it == 0) asm volatile("s_waitcnt vmcnt(0)" ::: "memory");
        else         asm volatile("s_waitcnt vmcnt(1)" ::: "memory");
        asm volatile("s_waitcnt lgkmcnt(0)" ::: "memory");
        __builtin_amdgcn_s_barrier();
        __builtin_amdgcn_sched_barrier(0);

        // ---- C-copy store (prev slice) ----
        if (it > 0) *(float4*)(out + cpo + dofs) = cpv;
        // ---- prefetch: K 2-ahead, V 1-ahead ----
        if (it < 14) stageK(it + 2);
        if (it < 15) stageV(it + 1);
        __builtin_amdgcn_sched_barrier(0);   // pin: stages issued before C-load
        cpo = cbase + (size_t)(it * 16 + 2 * wid + lh) * 4096;
        cpv = *(const float4*)(Cf + cpo);

        // ---- PV(it) || QK(it+1): interleaved independent MFMA streams ----
        const ushort_t* Vb = smem + 32768 + (it & 1) * 16384 + z * 8192;   // e-half z
        const ushort_t* Kb = smem + ((it + 1) & 1) * 16384 + z * 8192;     // kv-frag z
        const ushort_t* Pr = &Pl[it & 1][0];
        __builtin_amdgcn_s_setprio(1);
        if (it < 15) {
            f32x16 sn = zero16();
#pragma unroll
            for (int j = 0; j < 4; ++j) {
                short8 pf = *(const short8*)(Pr + ((size_t)(qg * 4 + j) * 64 + lane) * 8);
#pragma unroll
                for (int fl = 0; fl < 4; ++fl) {
                    short8 vf = *(const short8*)(Vb + (size_t)fl * 2048 + j * 512 + lane * 8);
                    o[fl] = __builtin_amdgcn_mfma_f32_32x32x16_bf16(vf, pf, o[fl], 0, 0, 0);
                    int ks = j * 4 + fl;
                    short8 kf = *(const short8*)(Kb + (size_t)ks * 512 + lane * 8);
                    sn = __builtin_amdgcn_mfma_f32_32x32x16_bf16(kf, qf[ks], sn, 0, 0, 0);
                }
            }
            s = sn;
        } else {
#pragma unroll
            for (int j = 0; j < 4; ++j) {
                short8 pf = *(const short8*)(Pr + ((size_t)(qg * 4 + j) * 64 + lane) * 8);
#pragma unroll
                for (int fl = 0; fl < 4; ++fl) {
                    short8 vf = *(const short8*)(Vb + (size_t)fl * 2048 + j * 512 + lane * 8);
                    o[fl] = __builtin_amdgcn_mfma_f32_32x32x16_bf16(vf, pf, o[fl], 0, 0, 0);
                }
            }
        }
        __builtin_amdgcn_s_setprio(0);
        __builtin_amdgcn_sched_barrier(0);
        // no B2: Pl double-buffered; K/V reuse ordered by next iteration's B1
    }

    *(float4*)(out + cpo + dofs) = cpv;   // last copy slice

    // ---- merge rl halves via dead smem, normalized store ----
    __syncthreads();                       // all compute done; smem reusable
    float* rlS = (float*)smem;             // [z][qg][l31] -> 256 floats
    if (lane < 32) rlS[(z * 4 + qg) * 32 + l31] = rl;
    __syncthreads();
    float inv = 1.f / (rlS[(0 * 4 + qg) * 32 + l31] + rlS[(1 * 4 + qg) * 32 + l31]);
    float* ob = out + (size_t)b * 2097152 + (size_t)256 * 4096 + qt * 128 + qg * 32 + l31;
#pragma unroll
    for (int fl = 0; fl < 4; ++fl) {
#pragma unroll
        for (int r = 0; r < 16; ++r) {
            int e = z * 128 + fl * 32 + (r & 3) + 8 * (r >> 2) + 4 * lh;
            ob[(size_t)e * 4096] = o[fl][r] * inv;
        }
    }
}

// ---------------- launch ----------------

extern "C" void kernel_launch(void* const* d_in, const int* in_sizes, int n_in,
                              void* d_out, int out_size, void* d_ws, size_t ws_size,
                              hipStream_t stream) {
    const float* C       = (const float*)d_in[0];
    const float* P       = (const float*)d_in[1];
    const float* theta_w = (const float*)d_in[2];
    const float* phi_w   = (const float*)d_in[3];
    const float* g_w     = (const float*)d_in[4];
    const float* out_w   = (const float*)d_in[5];
    float* out = (float*)d_out;

    ushort_t* ws = (ushort_t*)d_ws;
    ushort_t* thetaA = ws;                        // 8,388,608
    ushort_t* phiA   = ws + 8388608;              // 2,097,152
    ushort_t* gVx    = ws + 10485760;             // 2,097,152
    ushort_t* thWc   = ws + 12582912;             // 65,536
    ushort_t* phWc   = ws + 12648448;             // 65,536
    ushort_t* w2c    = ws + 12713984;             // 65,536

    prep_w<<<96, 256, 0, stream>>>(theta_w, phi_w, out_w, g_w, thWc, phWc, w2c);
    proj_all<<<768, 256, 0, stream>>>(thWc, phWc, w2c, C, P, thetaA, phiA, gVx);
    attn14<<<256, 512, 0, stream>>>(thetaA, phiA, gVx, C, out);
}